// Round 6
// baseline (121.680 us; speedup 1.0000x reference)
//
#include <hip/hip_runtime.h>

#define NN 192
#define BZ 4
#define YC 12
#define NTHR (64 * BZ)

// x is mapped across the 64 lanes of a wave, 3 floats/lane (192 = 64*3).
// z-fold-first: for each (x, y-plane) fold the z-triple into
//   p = r(z-1)+r(z)+r(z+1)   (z-box)
//   q = r(z+1)-r(z-1)        (z-diff)
// then all remaining stencil work is on p/q only:
//   Gx = S(x+1)-S(x-1),          S = y-box of p
//   Gy = D(x-1)+D(x)+D(x+1),     D = y-diff of p
//   Gz = T(x-1)+T(x)+T(x+1),     T = y-box of q
// The x-halo of p/q is fetched from neighbor lanes via shuffle at fold time
// and stored in extended 5-wide slot arrays pe/qe = [L,0,1,2,R].
//
// Raw (un-halved) gradients: rawG = 2*trueG; the 0.5^2 factors cancel in ngf
// when EPS^2 (0.01) is replaced by 4*EPS^2 = 0.04.

__device__ __forceinline__ void fold_pq(const float3 rm, const float3 r0, const float3 rp,
                                        int lane, float pe[5], float qe[5]) {
    const float p0 = rm.x + r0.x + rp.x;
    const float p1 = rm.y + r0.y + rp.y;
    const float p2 = rm.z + r0.z + rp.z;
    const float q0 = rp.x - rm.x;
    const float q1 = rp.y - rm.y;
    const float q2 = rp.z - rm.z;
    float pL = __shfl_up(p2, 1, 64);
    float pR = __shfl_down(p0, 1, 64);
    float qL = __shfl_up(q2, 1, 64);
    float qR = __shfl_down(q0, 1, 64);
    if (lane == 0)  { pL = p0; qL = q0; }   // clamp x=-1 -> 0
    if (lane == 63) { pR = p2; qR = q2; }   // clamp x=192 -> 191
    pe[0] = pL; pe[1] = p0; pe[2] = p1; pe[3] = p2; pe[4] = pR;
    qe[0] = qL; qe[1] = q0; qe[2] = q1; qe[3] = q2; qe[4] = qR;
}

__device__ __forceinline__ void load_plane(const float* const base[6], int yrow,
                                           float3 rI[3], float3 rJ[3]) {
#pragma unroll
    for (int d = 0; d < 3; ++d) rI[d] = *reinterpret_cast<const float3*>(base[d] + yrow);
#pragma unroll
    for (int d = 0; d < 3; ++d) rJ[d] = *reinterpret_cast<const float3*>(base[3 + d] + yrow);
}

__global__ __launch_bounds__(NTHR, 3) void ngf_kernel(const float* __restrict__ I,
                                                      const float* __restrict__ J,
                                                      const float* __restrict__ M,
                                                      float* __restrict__ out) {
    const int lane = threadIdx.x;         // 0..63
    const int tz = threadIdx.y;
    const int xoff = lane * 3;
    const int z = blockIdx.y * BZ + tz;
    const int ybase = blockIdx.x * YC;

    const int gzm = (z == 0) ? 0 : z - 1;
    const int gzp = (z == NN - 1) ? (NN - 1) : z + 1;

    const float* base[6] = {
        I + gzm * NN * NN + xoff, I + z * NN * NN + xoff, I + gzp * NN * NN + xoff,
        J + gzm * NN * NN + xoff, J + z * NN * NN + xoff, J + gzp * NN * NN + xoff};
    const float* mbase = M + z * NN * NN + xoff;

    // rotating slots: [array][slot][5]  (x-extended p and q)
    float pe[2][3][5], qe[2][3][5];

    // ---- seed: fold plane y=ybase-1 (clamped) -> slot 0, y=ybase -> slot 1
    {
        float3 rI[3], rJ[3];
        load_plane(base, ((ybase == 0) ? 0 : (ybase - 1)) * NN, rI, rJ);
        fold_pq(rI[0], rI[1], rI[2], lane, pe[0][0], qe[0][0]);
        fold_pq(rJ[0], rJ[1], rJ[2], lane, pe[1][0], qe[1][0]);
        load_plane(base, ybase * NN, rI, rJ);
        fold_pq(rI[0], rI[1], rI[2], lane, pe[0][1], qe[0][1]);
        fold_pq(rJ[0], rJ[1], rJ[2], lane, pe[1][1], qe[1][1]);
    }

    // raw-plane double buffer; prefetch plane ybase+1 (<= 190 < 192)
    float3 bI[2][3], bJ[2][3];
    load_plane(base, (ybase + 1) * NN, bI[0], bJ[0]);
    float3 mcur = *reinterpret_cast<const float3*>(mbase + ybase * NN);

    float acc = 0.0f;
#pragma unroll
    for (int yy = 0; yy < YC; ++yy) {
        const int cb = yy & 1, nb = cb ^ 1;   // constant after unroll

        // 1) issue next plane's loads (consumed next iteration)
        float3 mnxt = mcur;
        if (yy < YC - 1) {
            int gy = ybase + yy + 2;
            gy = (gy > NN - 1) ? (NN - 1) : gy;
            load_plane(base, gy * NN, bI[nb], bJ[nb]);
            mnxt = *reinterpret_cast<const float3*>(mbase + (ybase + yy + 1) * NN);
        }

        // 2) fold plane y = ybase+yy+1 (loads issued one step ago) -> slot sC
        const int sC = (yy + 2) % 3;
        fold_pq(bI[cb][0], bI[cb][1], bI[cb][2], lane, pe[0][sC], qe[0][sC]);
        fold_pq(bJ[cb][0], bJ[cb][1], bJ[cb][2], lane, pe[1][sC], qe[1][sC]);

        // 3) NGF at y = ybase+yy (slots yy-1+1.. live: s0=y-1, s1=y, sC=y+1)
        const int s0 = yy % 3, s1 = (yy + 1) % 3;
        float G[2][3][3];   // [array][Gx,Gy,Gz][voxel]
#pragma unroll
        for (int ar = 0; ar < 2; ++ar) {
            float S[5], D[5], T[5];
#pragma unroll
            for (int i = 0; i < 5; ++i) {
                S[i] = pe[ar][s0][i] + pe[ar][s1][i] + pe[ar][sC][i];
                D[i] = pe[ar][sC][i] - pe[ar][s0][i];
                T[i] = qe[ar][s0][i] + qe[ar][s1][i] + qe[ar][sC][i];
            }
#pragma unroll
            for (int i = 0; i < 3; ++i) {
                G[ar][0][i] = S[i + 2] - S[i];
                G[ar][1][i] = D[i] + D[i + 1] + D[i + 2];
                G[ar][2][i] = T[i] + T[i + 1] + T[i + 2];
            }
        }
        const float mm[3] = {mcur.x, mcur.y, mcur.z};
#pragma unroll
        for (int i = 0; i < 3; ++i) {
            const float Ix = G[0][0][i], Iy = G[0][1][i], Iz = G[0][2][i];
            const float Jx = G[1][0][i], Jy = G[1][1][i], Jz = G[1][2][i];
            const float im = Ix * Ix + Iy * Iy + Iz * Iz + 0.04f;
            const float jm = Jx * Jx + Jy * Jy + Jz * Jz + 0.04f;
            const float dot = Ix * Jx + Iy * Jy + Iz * Jz;
            acc += (1.0f - dot * dot * __builtin_amdgcn_rcpf(im * jm)) * mm[i];
        }
        mcur = mnxt;
    }

    // mean scaling, then wave -> block -> global reduction
    acc *= (1.0f / ((float)NN * (float)NN * (float)NN));
#pragma unroll
    for (int off = 32; off > 0; off >>= 1)
        acc += __shfl_down(acc, off, 64);

    __shared__ float red[NTHR / 64];
    const int flat = tz * 64 + lane;
    if ((flat & 63) == 0) red[flat >> 6] = acc;
    __syncthreads();
    if (flat == 0) {
        float s = 0.0f;
#pragma unroll
        for (int w = 0; w < NTHR / 64; ++w) s += red[w];
        atomicAdd(out, s);
    }
}

extern "C" void kernel_launch(void* const* d_in, const int* in_sizes, int n_in,
                              void* d_out, int out_size, void* d_ws, size_t ws_size,
                              hipStream_t stream) {
    const float* I = (const float*)d_in[0];
    const float* J = (const float*)d_in[1];
    const float* M = (const float*)d_in[2];
    float* out = (float*)d_out;

    hipMemsetAsync(d_out, 0, sizeof(float), stream);

    dim3 block(64, BZ);               // 256 threads = 4 waves
    dim3 grid(NN / YC, NN / BZ);      // (16, 48) = 768 blocks = 3 blocks/CU exactly
    ngf_kernel<<<grid, block, 0, stream>>>(I, J, M, out);
}